// Round 10
// baseline (7204.202 us; speedup 1.0000x reference)
//
#include <hip/hip_runtime.h>
#include <stdint.h>

#define NSAMP 16384
#define NSITE 2048
#define BM 256
#define BN 256
#define BK 32

typedef _Float16 f16x8 __attribute__((ext_vector_type(8)));
typedef float f32x16 __attribute__((ext_vector_type(16)));

__device__ __forceinline__ unsigned short f2h(float f) {
  _Float16 h = (_Float16)f;
  return __builtin_bit_cast(unsigned short, h);
}
__device__ __forceinline__ float h2f(unsigned short u) {
  return (float)__builtin_bit_cast(_Float16, u);
}

__device__ __forceinline__ void gload_lds16(const void* g, void* l) {
  __builtin_amdgcn_global_load_lds(
      (const __attribute__((address_space(1))) void*)g,
      (__attribute__((address_space(3))) void*)l, 16, 0, 0);
}

#define SBAR() __builtin_amdgcn_sched_barrier(0)
#define BAR()  do { SBAR(); __builtin_amdgcn_s_barrier(); SBAR(); } while (0)
#define WLGKM(N) do { asm volatile("s_waitcnt lgkmcnt(" #N ")" ::: "memory"); SBAR(); } while (0)
#define WVM(N)   do { asm volatile("s_waitcnt vmcnt(" #N ")" ::: "memory"); SBAR(); } while (0)

// ---------------------------------------------------------------------------
// Packed fragment-major layout for an [R x 2048] fp16 matrix M:
//   frag (rbG, kb) is 1 KiB: lane l holds M[rbG*32 + (l&31)][kb*16 + (l>>5)*8 + e]
//   short index = ((rbG*128 + kb)*64 + lane)*8 + e
// ---------------------------------------------------------------------------

__global__ void build_w_kernel(const float* __restrict__ kern,
                               unsigned short* __restrict__ Wp) {
  const int idx = blockIdx.x * blockDim.x + threadIdx.x;
  const int lane = idx & 63;
  const int kb = (idx >> 6) & 127;
  const int rbG = idx >> 13;
  const int j = rbG * 32 + (lane & 31);
  const int i0 = kb * 16 + (lane >> 5) * 8;
  const long long tri = (long long)j * (j - 1) / 2;
  unsigned short v[8];
#pragma unroll
  for (int e = 0; e < 8; ++e) {
    const int i = i0 + e;
    float f = (i < j) ? kern[tri + i] : 0.0f;
    v[e] = f2h(f);
  }
  ushort4* dst = (ushort4*)(Wp + (size_t)idx * 8);
  dst[0] = make_ushort4(v[0], v[1], v[2], v[3]);
  dst[1] = make_ushort4(v[4], v[5], v[6], v[7]);
}

__global__ void build_x_kernel(const float* __restrict__ x,
                               unsigned short* __restrict__ Xp,
                               unsigned short* __restrict__ Xrow) {
  const int idx = blockIdx.x * blockDim.x + threadIdx.x;
  const int row = idx >> 8;
  const int c8 = idx & 255;
  const float4 v0 = ((const float4*)x)[(size_t)idx * 2];
  const float4 v1 = ((const float4*)x)[(size_t)idx * 2 + 1];
  const ushort4 h0 = make_ushort4(f2h(v0.x), f2h(v0.y), f2h(v0.z), f2h(v0.w));
  const ushort4 h1 = make_ushort4(f2h(v1.x), f2h(v1.y), f2h(v1.z), f2h(v1.w));
  ushort4* dr = (ushort4*)(Xrow + (size_t)idx * 8);
  dr[0] = h0;
  dr[1] = h1;
  const int rbG = row >> 5, kb = c8 >> 1;
  const int lane = (c8 & 1) * 32 + (row & 31);
  ushort4* dp = (ushort4*)(Xp + (((size_t)rbG * 128 + kb) * 64 + lane) * 8);
  dp[0] = h0;
  dp[1] = h1;
}

// 256x256 tile, 8 waves (2M x 4N, wave 128x64), BK=32, 32x32x16 fp16 MFMA.
// Both operands frag-major -> LDS (ring-2 of 32KB slots, 64KB -> 2 blocks/CU).
// XCD-cohort mapping: xcd=bid&7; XCD pair p covers nt in {7-p, p} (balanced),
// dispatch alternates heavy/light -> W slices stay L2-resident per XCD.
template <int EPI>
__global__ __launch_bounds__(512, 4) void gemm_pass(
    const unsigned short* __restrict__ Ap, const unsigned short* __restrict__ Wp,
    const unsigned short* __restrict__ Xrow, unsigned short* __restrict__ Pp,
    float* __restrict__ out) {
  __shared__ unsigned short lds[2 * 16384];  // 2 x 32 KiB

  const int bid = blockIdx.x;            // 512 blocks
  const int xcd = bid & 7, slot = bid >> 3;
  const int p = xcd >> 1, mhalf = xcd & 1;
  const int nt = (slot & 1) ? p : (7 - p);
  const int mt = (slot >> 1) + mhalf * 32;
  const int m0 = mt * BM, n0 = nt * BN;

  const int tid = threadIdx.x, lane = tid & 63, wid = tid >> 6;
  const int wm = wid >> 2;   // 0..1: rows wm*128..
  const int wn = wid & 3;    // 0..3: cols wn*64..
  const int l32 = lane & 31, hi2 = lane >> 5;
  const int nkt = 8 * (nt + 1);  // strictly-lower-tri K cut

  f32x16 acc[4][2] = {};  // [mb][nb], 128 VGPR

  // staging: thread covers frag fi = wid and 8+wid of each slot (A and W)
  const int rbG0 = m0 >> 5, cbG0 = n0 >> 5;
  const int fh = wid >> 1, ks = wid & 1;
  const unsigned short* srcA0 = Ap + (((size_t)(rbG0 + fh) * 128 + ks) * 64 + lane) * 8;
  const unsigned short* srcA1 = Ap + (((size_t)(rbG0 + 4 + fh) * 128 + ks) * 64 + lane) * 8;
  const unsigned short* srcW0 = Wp + (((size_t)(cbG0 + fh) * 128 + ks) * 64 + lane) * 8;
  const unsigned short* srcW1 = Wp + (((size_t)(cbG0 + 4 + fh) * 128 + ks) * 64 + lane) * 8;
  const int d0 = wid * 1024 + lane * 16;
  const int d1 = (8 + wid) * 1024 + lane * 16;

  auto STAGE = [&](int kidx, int sb) {
    const size_t ko = (size_t)kidx * 1024;  // shorts: 2 kb per K-step
    gload_lds16(srcA0 + ko, (char*)lds + sb + d0);
    gload_lds16(srcA1 + ko, (char*)lds + sb + d1);
    gload_lds16(srcW0 + ko, (char*)lds + sb + 16384 + d0);
    gload_lds16(srcW1 + ko, (char*)lds + sb + 16384 + d1);
  };

  STAGE(0, 0);
  WVM(0);
  BAR();

  int sb = 0;
  for (int t = 0; t < nkt; ++t) {
    if (t + 1 < nkt) STAGE(t + 1, sb ^ 32768);
    f16x8 fa0[4], fa1[4], fb0[2], fb1[2];
    // ksub0 reads first (6), then ksub1 (6) — all uniform-base + lane*16
#pragma unroll
    for (int mb = 0; mb < 4; ++mb)
      fa0[mb] = *(const f16x8*)((char*)lds + sb + ((wm * 4 + mb) * 2 + 0) * 1024 + lane * 16);
#pragma unroll
    for (int nb = 0; nb < 2; ++nb)
      fb0[nb] = *(const f16x8*)((char*)lds + sb + 16384 + ((wn * 2 + nb) * 2 + 0) * 1024 + lane * 16);
#pragma unroll
    for (int mb = 0; mb < 4; ++mb)
      fa1[mb] = *(const f16x8*)((char*)lds + sb + ((wm * 4 + mb) * 2 + 1) * 1024 + lane * 16);
#pragma unroll
    for (int nb = 0; nb < 2; ++nb)
      fb1[nb] = *(const f16x8*)((char*)lds + sb + 16384 + ((wn * 2 + nb) * 2 + 1) * 1024 + lane * 16);
    WLGKM(6);  // ksub0 frags ready
    __builtin_amdgcn_s_setprio(1);
#pragma unroll
    for (int mb = 0; mb < 4; ++mb)
#pragma unroll
      for (int nb = 0; nb < 2; ++nb)
        acc[mb][nb] = __builtin_amdgcn_mfma_f32_32x32x16_f16(fa0[mb], fb0[nb], acc[mb][nb], 0, 0, 0);
    WLGKM(0);  // ksub1 frags ready
#pragma unroll
    for (int mb = 0; mb < 4; ++mb)
#pragma unroll
      for (int nb = 0; nb < 2; ++nb)
        acc[mb][nb] = __builtin_amdgcn_mfma_f32_32x32x16_f16(fa1[mb], fb1[nb], acc[mb][nb], 0, 0, 0);
    __builtin_amdgcn_s_setprio(0);
    WVM(0);  // next slot landed (overlapped with this step's reads+MFMA)
    BAR();
    sb ^= 32768;
  }

  BAR();  // ring idle before epilogue reuses LDS

  // C/D layout 32x32: col = lane&31, row = (reg&3)+8*(reg>>2)+4*(lane>>5)
  const int ebase = wid * 4096;  // per-wave 4KB scratch
  if (EPI == 0) {
#pragma unroll
    for (int mb = 0; mb < 4; ++mb) {
      const int growb = m0 + wm * 128 + mb * 32;
#pragma unroll
      for (int nb = 0; nb < 2; ++nb)
#pragma unroll
        for (int r = 0; r < 16; ++r) {
          const int row = (r & 3) + 8 * (r >> 2) + 4 * hi2;
          const int col = nb * 32 + l32;
          const unsigned short xv =
              Xrow[(size_t)(growb + row) * NSITE + n0 + wn * 64 + col];
          const unsigned short pv = f2h(acc[mb][nb][r] * h2f(xv));
          *(volatile unsigned short*)((char*)lds + ebase + row * 128 + col * 2) = pv;
        }
      WLGKM(0);
      const int rbG = growb >> 5;
#pragma unroll
      for (int kbl = 0; kbl < 4; ++kbl) {
        f16x8 fr = *(const f16x8*)((char*)lds + ebase + l32 * 128 + kbl * 32 + hi2 * 16);
        const int kbG = ((n0 + wn * 64) >> 4) + kbl;
        *(f16x8*)(Pp + (((size_t)rbG * 128 + kbG) * 64 + lane) * 8) = fr;
      }
      WLGKM(0);
    }
  } else {
#pragma unroll
    for (int mb = 0; mb < 4; ++mb) {
      const int growb = m0 + wm * 128 + mb * 32;
#pragma unroll
      for (int r = 0; r < 16; ++r) {
        const int row = (r & 3) + 8 * (r >> 2) + 4 * hi2;
        const int grow = growb + row;
        const size_t xb = (size_t)grow * NSITE + n0 + wn * 64 + l32;
        float s = acc[mb][0][r] * h2f(Xrow[xb]) + acc[mb][1][r] * h2f(Xrow[xb + 32]);
        s += __shfl_xor(s, 1);
        s += __shfl_xor(s, 2);
        s += __shfl_xor(s, 4);
        s += __shfl_xor(s, 8);
        s += __shfl_xor(s, 16);
        if (l32 == 0) atomicAdd(&out[grow], s);
      }
    }
  }
}

extern "C" void kernel_launch(void* const* d_in, const int* in_sizes, int n_in,
                              void* d_out, int out_size, void* d_ws, size_t ws_size,
                              hipStream_t stream) {
  const float* x = (const float*)d_in[0];
  const float* kern = (const float*)d_in[1];
  float* out = (float*)d_out;

  unsigned short* Wp   = (unsigned short*)d_ws;             // N*N fp16 packed
  unsigned short* Xp   = Wp + (size_t)NSITE * NSITE;        // NS*N packed
  unsigned short* Xrow = Xp + (size_t)NSAMP * NSITE;        // NS*N row-major
  unsigned short* P1   = Xrow + (size_t)NSAMP * NSITE;      // NS*N packed
  unsigned short* P2   = P1 + (size_t)NSAMP * NSITE;        // NS*N packed

  hipMemsetAsync(d_out, 0, (size_t)NSAMP * sizeof(float), stream);
  build_w_kernel<<<(NSITE * NSITE / 8) / 256, 256, 0, stream>>>(kern, Wp);
  build_x_kernel<<<(NSAMP * NSITE / 8) / 256, 256, 0, stream>>>(x, Xp, Xrow);

  // pass 1: z1 = x @ W^T ; P1 = pack(fp16(z1 * x))
  gemm_pass<0><<<512, 512, 0, stream>>>(Xp, Wp, Xrow, P1, nullptr);
  // pass 2: z2 = P1 @ W^T ; P2 = pack(fp16(z2 * x))
  gemm_pass<0><<<512, 512, 0, stream>>>(P1, Wp, Xrow, P2, nullptr);
  // pass 3: z3 = P2 @ W^T ; out[n] = sum_j z3 * x
  gemm_pass<1><<<512, 512, 0, stream>>>(P2, Wp, Xrow, nullptr, out);
}

// Round 11
// 556.310 us; speedup vs baseline: 12.9500x; 12.9500x over previous
//
#include <hip/hip_runtime.h>
#include <stdint.h>

#define NSAMP 16384
#define NSITE 2048

typedef _Float16 f16x8 __attribute__((ext_vector_type(8)));
typedef float f32x16 __attribute__((ext_vector_type(16)));

__device__ __forceinline__ unsigned short f2h(float f) {
  _Float16 h = (_Float16)f;
  return __builtin_bit_cast(unsigned short, h);
}
__device__ __forceinline__ float h2f(unsigned short u) {
  return (float)__builtin_bit_cast(_Float16, u);
}

__device__ __forceinline__ void gload_lds16(const void* g, void* l) {
  __builtin_amdgcn_global_load_lds(
      (const __attribute__((address_space(1))) void*)g,
      (__attribute__((address_space(3))) void*)l, 16, 0, 0);
}

#define SBAR() __builtin_amdgcn_sched_barrier(0)
#define BAR()  do { SBAR(); __builtin_amdgcn_s_barrier(); SBAR(); } while (0)
#define WLGKM(N) do { asm volatile("s_waitcnt lgkmcnt(" #N ")" ::: "memory"); SBAR(); } while (0)
#define WVM(N)   do { asm volatile("s_waitcnt vmcnt(" #N ")" ::: "memory"); SBAR(); } while (0)

// ---------------------------------------------------------------------------
// Packed fragment-major layout for an [R x 2048] fp16 matrix M:
//   frag (rbG, kb) is 1 KiB: lane l holds M[rbG*32 + (l&31)][kb*16 + (l>>5)*8 + e]
//   short index = ((rbG*128 + kb)*64 + lane)*8 + e
// ---------------------------------------------------------------------------

__global__ void build_w_kernel(const float* __restrict__ kern,
                               unsigned short* __restrict__ Wp) {
  const int idx = blockIdx.x * blockDim.x + threadIdx.x;
  const int lane = idx & 63;
  const int kb = (idx >> 6) & 127;
  const int rbG = idx >> 13;
  const int j = rbG * 32 + (lane & 31);
  const int i0 = kb * 16 + (lane >> 5) * 8;
  const long long tri = (long long)j * (j - 1) / 2;
  unsigned short v[8];
#pragma unroll
  for (int e = 0; e < 8; ++e) {
    const int i = i0 + e;
    float f = (i < j) ? kern[tri + i] : 0.0f;
    v[e] = f2h(f);
  }
  ushort4* dst = (ushort4*)(Wp + (size_t)idx * 8);
  dst[0] = make_ushort4(v[0], v[1], v[2], v[3]);
  dst[1] = make_ushort4(v[4], v[5], v[6], v[7]);
}

__global__ void build_x_kernel(const float* __restrict__ x,
                               unsigned short* __restrict__ Xp,
                               unsigned short* __restrict__ Xrow) {
  const int idx = blockIdx.x * blockDim.x + threadIdx.x;
  const int row = idx >> 8;
  const int c8 = idx & 255;
  const float4 v0 = ((const float4*)x)[(size_t)idx * 2];
  const float4 v1 = ((const float4*)x)[(size_t)idx * 2 + 1];
  const ushort4 h0 = make_ushort4(f2h(v0.x), f2h(v0.y), f2h(v0.z), f2h(v0.w));
  const ushort4 h1 = make_ushort4(f2h(v1.x), f2h(v1.y), f2h(v1.z), f2h(v1.w));
  ushort4* dr = (ushort4*)(Xrow + (size_t)idx * 8);
  dr[0] = h0;
  dr[1] = h1;
  const int rbG = row >> 5, kb = c8 >> 1;
  const int lane = (c8 & 1) * 32 + (row & 31);
  ushort4* dp = (ushort4*)(Xp + (((size_t)rbG * 128 + kb) * 64 + lane) * 8);
  dp[0] = h0;
  dp[1] = h1;
}

// 256x256 tile, ONE 1024-thread block (16 waves, 4x4 grid of 64x64 wave tiles).
// Both operands frag-major -> LDS via gload_lds (wave stages its own A+W frag).
// LDS = ring-5 x 32KB = 160KB (full pool): 3-step prefetch, steady vmcnt(6),
// one barrier per K-step. acc 64 regs + 16 live frag regs -> <=128 total
// -> 16 waves/CU. XCD pairing: xcd=bid&7, pair p covers nt {7-p, p} (balanced,
// W slices 2MB L2-resident per XCD).
template <int EPI>
__global__ __launch_bounds__(1024, 4) void gemm_pass(
    const unsigned short* __restrict__ Ap, const unsigned short* __restrict__ Wp,
    const unsigned short* __restrict__ Xrow, unsigned short* __restrict__ Pp,
    float* __restrict__ out) {
  __shared__ unsigned short lds[5 * 16384];  // 163840 B

  const int bid = blockIdx.x;  // 512 blocks
  const int xcd = bid & 7, bslot = bid >> 3;
  const int p = xcd >> 1, mhalf = xcd & 1;
  const int nt = (bslot & 1) ? p : (7 - p);
  const int mt = (bslot >> 1) + mhalf * 32;
  const int m0 = mt * 256, n0 = nt * 256;

  const int tid = threadIdx.x, lane = tid & 63, wid = tid >> 6;  // wid 0..15
  const int wr = wid >> 2, wc = wid & 3;  // wave tile rows wr*64, cols wc*64
  const int l32 = lane & 31, hi2 = lane >> 5;
  const int nkt = 8 * (nt + 1);  // strictly-lower-tri K cut (>= 8)

  f32x16 acc[2][2] = {};  // 64 regs

  // wave wid stages A-frag wid and W-frag wid (1 KiB each) per K-step
  const int rbG0 = m0 >> 5, cbG0 = n0 >> 5;
  const unsigned short* srcA =
      Ap + (((size_t)(rbG0 + (wid >> 1)) * 128 + (wid & 1)) * 64 + lane) * 8;
  const unsigned short* srcW =
      Wp + (((size_t)(cbG0 + (wid >> 1)) * 128 + (wid & 1)) * 64 + lane) * 8;
  const int dA = wid * 1024 + lane * 16;
  const int dW = 16384 + wid * 1024 + lane * 16;

  auto STAGE = [&](int kidx, int sb) {
    gload_lds16(srcA + (size_t)kidx * 1024, (char*)lds + sb + dA);
    gload_lds16(srcW + (size_t)kidx * 1024, (char*)lds + sb + dW);
  };

  STAGE(0, 0);
  STAGE(1, 32768);
  STAGE(2, 65536);

  int rb_ = 0, wb_ = 3 * 32768;  // read-slot base, write-slot base (bytes)
  for (int t = 0; t < nkt; ++t) {
    if (t + 3 < nkt) STAGE(t + 3, wb_);
    if (t + 4 <= nkt) { WVM(6); }
    else if (t + 3 == nkt) { WVM(4); }
    else if (t + 2 == nkt) { WVM(2); }
    else { WVM(0); }
    BAR();
    const char* Ls = (const char*)lds + rb_;
    // ---- ksub 0: 4 reads (uniform base + lane*16, conflict-free) + 4 MFMA
    {
      f16x8 fa0 = *(const f16x8*)(Ls + ((wr * 2 + 0) * 2 + 0) * 1024 + lane * 16);
      f16x8 fa1 = *(const f16x8*)(Ls + ((wr * 2 + 1) * 2 + 0) * 1024 + lane * 16);
      f16x8 fb0 = *(const f16x8*)(Ls + 16384 + ((wc * 2 + 0) * 2 + 0) * 1024 + lane * 16);
      f16x8 fb1 = *(const f16x8*)(Ls + 16384 + ((wc * 2 + 1) * 2 + 0) * 1024 + lane * 16);
      WLGKM(0);
      __builtin_amdgcn_s_setprio(1);
      acc[0][0] = __builtin_amdgcn_mfma_f32_32x32x16_f16(fa0, fb0, acc[0][0], 0, 0, 0);
      acc[0][1] = __builtin_amdgcn_mfma_f32_32x32x16_f16(fa0, fb1, acc[0][1], 0, 0, 0);
      acc[1][0] = __builtin_amdgcn_mfma_f32_32x32x16_f16(fa1, fb0, acc[1][0], 0, 0, 0);
      acc[1][1] = __builtin_amdgcn_mfma_f32_32x32x16_f16(fa1, fb1, acc[1][1], 0, 0, 0);
      __builtin_amdgcn_s_setprio(0);
    }
    // ---- ksub 1
    {
      f16x8 fa0 = *(const f16x8*)(Ls + ((wr * 2 + 0) * 2 + 1) * 1024 + lane * 16);
      f16x8 fa1 = *(const f16x8*)(Ls + ((wr * 2 + 1) * 2 + 1) * 1024 + lane * 16);
      f16x8 fb0 = *(const f16x8*)(Ls + 16384 + ((wc * 2 + 0) * 2 + 1) * 1024 + lane * 16);
      f16x8 fb1 = *(const f16x8*)(Ls + 16384 + ((wc * 2 + 1) * 2 + 1) * 1024 + lane * 16);
      WLGKM(0);
      __builtin_amdgcn_s_setprio(1);
      acc[0][0] = __builtin_amdgcn_mfma_f32_32x32x16_f16(fa0, fb0, acc[0][0], 0, 0, 0);
      acc[0][1] = __builtin_amdgcn_mfma_f32_32x32x16_f16(fa0, fb1, acc[0][1], 0, 0, 0);
      acc[1][0] = __builtin_amdgcn_mfma_f32_32x32x16_f16(fa1, fb0, acc[1][0], 0, 0, 0);
      acc[1][1] = __builtin_amdgcn_mfma_f32_32x32x16_f16(fa1, fb1, acc[1][1], 0, 0, 0);
      __builtin_amdgcn_s_setprio(0);
    }
    rb_ += 32768; if (rb_ == 5 * 32768) rb_ = 0;
    wb_ += 32768; if (wb_ == 5 * 32768) wb_ = 0;
  }

  BAR();  // ring idle before epilogue reuses LDS

  // C/D layout 32x32: col = lane&31, row = (reg&3)+8*(reg>>2)+4*(lane>>5)
  const int ebase = wid * 4096;  // 16 waves x 4KB = 64KB scratch
  if (EPI == 0) {
#pragma unroll
    for (int mb = 0; mb < 2; ++mb) {
      const int growb = m0 + wr * 64 + mb * 32;
#pragma unroll
      for (int nb = 0; nb < 2; ++nb)
#pragma unroll
        for (int r = 0; r < 16; ++r) {
          const int row = (r & 3) + 8 * (r >> 2) + 4 * hi2;
          const int col = nb * 32 + l32;
          const unsigned short xv =
              Xrow[(size_t)(growb + row) * NSITE + n0 + wc * 64 + col];
          const unsigned short pv = f2h(acc[mb][nb][r] * h2f(xv));
          *(volatile unsigned short*)((char*)lds + ebase + row * 128 + col * 2) = pv;
        }
      WLGKM(0);  // wave-local: writes visible to own reads
      const int rbG = growb >> 5;
#pragma unroll
      for (int kbl = 0; kbl < 4; ++kbl) {
        f16x8 fr = *(const f16x8*)((char*)lds + ebase + l32 * 128 + kbl * 32 + hi2 * 16);
        const int kbG = ((n0 + wc * 64) >> 4) + kbl;
        *(f16x8*)(Pp + (((size_t)rbG * 128 + kbG) * 64 + lane) * 8) = fr;
      }
      WLGKM(0);  // reads done before next mb overwrites region
    }
  } else {
#pragma unroll
    for (int mb = 0; mb < 2; ++mb) {
      const int growb = m0 + wr * 64 + mb * 32;
#pragma unroll
      for (int r = 0; r < 16; ++r) {
        const int row = (r & 3) + 8 * (r >> 2) + 4 * hi2;
        const int grow = growb + row;
        const size_t xb = (size_t)grow * NSITE + n0 + wc * 64 + l32;
        float s = acc[mb][0][r] * h2f(Xrow[xb]) + acc[mb][1][r] * h2f(Xrow[xb + 32]);
        s += __shfl_xor(s, 1);
        s += __shfl_xor(s, 2);
        s += __shfl_xor(s, 4);
        s += __shfl_xor(s, 8);
        s += __shfl_xor(s, 16);
        if (l32 == 0) atomicAdd(&out[grow], s);
      }
    }
  }
}

extern "C" void kernel_launch(void* const* d_in, const int* in_sizes, int n_in,
                              void* d_out, int out_size, void* d_ws, size_t ws_size,
                              hipStream_t stream) {
  const float* x = (const float*)d_in[0];
  const float* kern = (const float*)d_in[1];
  float* out = (float*)d_out;

  unsigned short* Wp   = (unsigned short*)d_ws;             // N*N fp16 packed
  unsigned short* Xp   = Wp + (size_t)NSITE * NSITE;        // NS*N packed
  unsigned short* Xrow = Xp + (size_t)NSAMP * NSITE;        // NS*N row-major
  unsigned short* P1   = Xrow + (size_t)NSAMP * NSITE;      // NS*N packed
  unsigned short* P2   = P1 + (size_t)NSAMP * NSITE;        // NS*N packed

  hipMemsetAsync(d_out, 0, (size_t)NSAMP * sizeof(float), stream);
  build_w_kernel<<<(NSITE * NSITE / 8) / 256, 256, 0, stream>>>(kern, Wp);
  build_x_kernel<<<(NSAMP * NSITE / 8) / 256, 256, 0, stream>>>(x, Xp, Xrow);

  // pass 1: z1 = x @ W^T ; P1 = pack(fp16(z1 * x))
  gemm_pass<0><<<512, 1024, 0, stream>>>(Xp, Wp, Xrow, P1, nullptr);
  // pass 2: z2 = P1 @ W^T ; P2 = pack(fp16(z2 * x))
  gemm_pass<0><<<512, 1024, 0, stream>>>(P1, Wp, Xrow, P2, nullptr);
  // pass 3: z3 = P2 @ W^T ; out[n] = sum_j z3 * x
  gemm_pass<1><<<512, 1024, 0, stream>>>(P2, Wp, Xrow, nullptr, out);
}

// Round 12
// 539.931 us; speedup vs baseline: 13.3428x; 1.0303x over previous
//
#include <hip/hip_runtime.h>
#include <stdint.h>

#define NSAMP 16384
#define NSITE 2048

typedef _Float16 f16x8 __attribute__((ext_vector_type(8)));
typedef float f32x16 __attribute__((ext_vector_type(16)));

__device__ __forceinline__ unsigned short f2h(float f) {
  _Float16 h = (_Float16)f;
  return __builtin_bit_cast(unsigned short, h);
}
__device__ __forceinline__ float h2f(unsigned short u) {
  return (float)__builtin_bit_cast(_Float16, u);
}

__device__ __forceinline__ void gload_lds16(const void* g, void* l) {
  __builtin_amdgcn_global_load_lds(
      (const __attribute__((address_space(1))) void*)g,
      (__attribute__((address_space(3))) void*)l, 16, 0, 0);
}

#define SBAR() __builtin_amdgcn_sched_barrier(0)
#define BAR()  do { SBAR(); __builtin_amdgcn_s_barrier(); SBAR(); } while (0)
#define WLGKM(N) do { asm volatile("s_waitcnt lgkmcnt(" #N ")" ::: "memory"); SBAR(); } while (0)
#define WVM(N)   do { asm volatile("s_waitcnt vmcnt(" #N ")" ::: "memory"); SBAR(); } while (0)

// ---------------------------------------------------------------------------
// Packed fragment-major layout for an [R x 2048] fp16 matrix M:
//   frag (rbG, kb) is 1 KiB: lane l holds M[rbG*32 + (l&31)][kb*16 + (l>>5)*8 + e]
//   short index = ((rbG*128 + kb)*64 + lane)*8 + e
// ---------------------------------------------------------------------------

__global__ void build_w_kernel(const float* __restrict__ kern,
                               unsigned short* __restrict__ Wp) {
  const int idx = blockIdx.x * blockDim.x + threadIdx.x;
  const int lane = idx & 63;
  const int kb = (idx >> 6) & 127;
  const int rbG = idx >> 13;
  const int j = rbG * 32 + (lane & 31);
  const int i0 = kb * 16 + (lane >> 5) * 8;
  const long long tri = (long long)j * (j - 1) / 2;
  unsigned short v[8];
#pragma unroll
  for (int e = 0; e < 8; ++e) {
    const int i = i0 + e;
    float f = (i < j) ? kern[tri + i] : 0.0f;
    v[e] = f2h(f);
  }
  ushort4* dst = (ushort4*)(Wp + (size_t)idx * 8);
  dst[0] = make_ushort4(v[0], v[1], v[2], v[3]);
  dst[1] = make_ushort4(v[4], v[5], v[6], v[7]);
}

__global__ void build_x_kernel(const float* __restrict__ x,
                               unsigned short* __restrict__ Xp,
                               unsigned short* __restrict__ Xrow) {
  const int idx = blockIdx.x * blockDim.x + threadIdx.x;
  const int row = idx >> 8;
  const int c8 = idx & 255;
  const float4 v0 = ((const float4*)x)[(size_t)idx * 2];
  const float4 v1 = ((const float4*)x)[(size_t)idx * 2 + 1];
  const ushort4 h0 = make_ushort4(f2h(v0.x), f2h(v0.y), f2h(v0.z), f2h(v0.w));
  const ushort4 h1 = make_ushort4(f2h(v1.x), f2h(v1.y), f2h(v1.z), f2h(v1.w));
  ushort4* dr = (ushort4*)(Xrow + (size_t)idx * 8);
  dr[0] = h0;
  dr[1] = h1;
  const int rbG = row >> 5, kb = c8 >> 1;
  const int lane = (c8 & 1) * 32 + (row & 31);
  ushort4* dp = (ushort4*)(Xp + (((size_t)rbG * 128 + kb) * 64 + lane) * 8);
  dp[0] = h0;
  dp[1] = h1;
}

// 64x256 tile, 4 waves (1M x 4N, wave 64x64), BK=32, 32x32x16 fp16 MFMA.
// A: frag-major -> LDS ring-3 x 4KB (1 gload/thread/step), conflict-free reads.
// W: frag-major global -> registers (4 x 1KiB coalesced L2 loads), 1-step dbuf.
// 16 KB LDS, ~145 VGPR, launch_bounds(256,3) -> 3 blocks/CU (12 waves).
// Counted waits: lgkm(2/0) chunks, end-of-step vmcnt(1). One barrier/step.
template <int EPI>
__global__ __launch_bounds__(256, 3) void gemm_pass(
    const unsigned short* __restrict__ Ap, const unsigned short* __restrict__ Wp,
    const unsigned short* __restrict__ Xrow, unsigned short* __restrict__ Pp,
    float* __restrict__ out) {
  __shared__ unsigned short lds[8192];  // 16 KiB: ring 3x4KB; epi scratch 4x4KB

  const int bid = blockIdx.x;  // 2048 blocks
  // balanced heavy/light pairing over nt: g: 0->7,1->0,2->6,3->1,4->5,5->2,6->4,7->3
  const int g = bid >> 8;
  const int nt = (g & 1) ? (g >> 1) : (7 - (g >> 1));
  const int mt = bid & 255;
  const int m0 = mt * 64, n0 = nt * 256;

  const int tid = threadIdx.x, lane = tid & 63, wid = tid >> 6;  // wid 0..3
  const int wn = wid;                 // wave cols wn*64
  const int l32 = lane & 31, hi2 = lane >> 5;
  const int nkt = 8 * (nt + 1);       // strictly-lower-tri K cut (8..64)

  f32x16 acc[2][2] = {};  // [mb][cb] rows mb*32, cols wn*64+cb*32 ; 64 VGPR

  // --- A staging: 1 gload/thread/step; frag f = tid>>6 (rb=f>>1, ks=f&1) ---
  const int rbG0 = m0 >> 5;  // = mt*2
  const int f = tid >> 6;
  const unsigned short* srcA =
      Ap + (((size_t)(rbG0 + (f >> 1)) * 128 + (f & 1)) * 64 + lane) * 8;

  // --- W pointers: frags (cb, ks) for this wave's 64 cols ---
  const int cb0 = (n0 >> 5) + wn * 2;
  const unsigned short* wp0 = Wp + (((size_t)(cb0 + 0) * 128 + 0) * 64 + lane) * 8;
  const unsigned short* wp1 = Wp + (((size_t)(cb0 + 0) * 128 + 1) * 64 + lane) * 8;
  const unsigned short* wp2 = Wp + (((size_t)(cb0 + 1) * 128 + 0) * 64 + lane) * 8;
  const unsigned short* wp3 = Wp + (((size_t)(cb0 + 1) * 128 + 1) * 64 + lane) * 8;

  // prologue: A(0), W(0), A(1); WVM(1) leaves A(1) in flight
  gload_lds16(srcA, (char*)lds + tid * 16);
  SBAR();
  f16x8 wc0 = *(const f16x8*)(wp0);
  f16x8 wc1 = *(const f16x8*)(wp1);
  f16x8 wc2 = *(const f16x8*)(wp2);
  f16x8 wc3 = *(const f16x8*)(wp3);
  SBAR();
  gload_lds16(srcA + 1024, (char*)lds + 4096 + tid * 16);
  WVM(1);
  BAR();

  int sbR = 0, sbW = 8192;  // byte bases of read slot (t) and write slot (t+2)
  for (int t = 0; t < nkt; ++t) {
    const char* Ls = (const char*)lds + sbR;
    // 1) issue W(t+1) register loads
    f16x8 wn0, wn1, wn2, wn3;
    const bool hasW = (t + 1 < nkt);
    if (hasW) {
      const size_t wo = (size_t)(t + 1) * 1024;  // shorts
      wn0 = *(const f16x8*)(wp0 + wo);
      wn1 = *(const f16x8*)(wp1 + wo);
      wn2 = *(const f16x8*)(wp2 + wo);
      wn3 = *(const f16x8*)(wp3 + wo);
    }
    SBAR();
    // 2) stage A(t+2) (1 gload/thread)
    if (t + 2 < nkt)
      gload_lds16(srcA + (size_t)(t + 2) * 1024, (char*)lds + sbW + tid * 16);
    // 3) ds_read A frags (uniform base + lane*16: conflict-free), chunked MFMA
    f16x8 fa00 = *(const f16x8*)(Ls + 0 * 1024 + lane * 16);  // mb0 ks0
    f16x8 fa10 = *(const f16x8*)(Ls + 2 * 1024 + lane * 16);  // mb1 ks0
    f16x8 fa01 = *(const f16x8*)(Ls + 1 * 1024 + lane * 16);  // mb0 ks1
    f16x8 fa11 = *(const f16x8*)(Ls + 3 * 1024 + lane * 16);  // mb1 ks1
    WLGKM(2);  // ks0 pair ready
    __builtin_amdgcn_s_setprio(1);
    acc[0][0] = __builtin_amdgcn_mfma_f32_32x32x16_f16(fa00, wc0, acc[0][0], 0, 0, 0);
    acc[0][1] = __builtin_amdgcn_mfma_f32_32x32x16_f16(fa00, wc2, acc[0][1], 0, 0, 0);
    acc[1][0] = __builtin_amdgcn_mfma_f32_32x32x16_f16(fa10, wc0, acc[1][0], 0, 0, 0);
    acc[1][1] = __builtin_amdgcn_mfma_f32_32x32x16_f16(fa10, wc2, acc[1][1], 0, 0, 0);
    WLGKM(0);  // ks1 pair ready
    acc[0][0] = __builtin_amdgcn_mfma_f32_32x32x16_f16(fa01, wc1, acc[0][0], 0, 0, 0);
    acc[0][1] = __builtin_amdgcn_mfma_f32_32x32x16_f16(fa01, wc3, acc[0][1], 0, 0, 0);
    acc[1][0] = __builtin_amdgcn_mfma_f32_32x32x16_f16(fa11, wc1, acc[1][0], 0, 0, 0);
    acc[1][1] = __builtin_amdgcn_mfma_f32_32x32x16_f16(fa11, wc3, acc[1][1], 0, 0, 0);
    __builtin_amdgcn_s_setprio(0);
    // 4) end-of-step: wait (counted), swap W AFTER the wait, barrier
    if (hasW) {
      if (t + 2 < nkt) { WVM(1); } else { WVM(0); }
      wc0 = wn0; wc1 = wn1; wc2 = wn2; wc3 = wn3;
      BAR();
    }
    sbR = (sbR == 8192) ? 0 : sbR + 4096;
    sbW = (sbW == 8192) ? 0 : sbW + 4096;
  }

  BAR();  // ring idle before epilogue reuses LDS

  // C/D layout 32x32: col = lane&31, row = (reg&3)+8*(reg>>2)+4*(lane>>5)
  const int ebase = wid * 4096;  // 4 waves x 4KB scratch
  if (EPI == 0) {
#pragma unroll
    for (int mb = 0; mb < 2; ++mb) {
      const int growb = m0 + mb * 32;
#pragma unroll
      for (int nb = 0; nb < 2; ++nb)
#pragma unroll
        for (int r = 0; r < 16; ++r) {
          const int row = (r & 3) + 8 * (r >> 2) + 4 * hi2;
          const int col = nb * 32 + l32;
          const unsigned short xv =
              Xrow[(size_t)(growb + row) * NSITE + n0 + wn * 64 + col];
          const unsigned short pv = f2h(acc[mb][nb][r] * h2f(xv));
          const int cbyte = (col * 2) ^ ((row & 7) << 4);  // epi swizzle
          *(volatile unsigned short*)((char*)lds + ebase + row * 128 + cbyte) = pv;
        }
      WLGKM(0);  // wave-local visibility
      const int rbG = growb >> 5;
#pragma unroll
      for (int kbl = 0; kbl < 4; ++kbl) {
        const int cbyteR = (kbl * 32 + hi2 * 16) ^ ((l32 & 7) << 4);
        f16x8 fr = *(const f16x8*)((char*)lds + ebase + l32 * 128 + cbyteR);
        const int kbG = ((n0 + wn * 64) >> 4) + kbl;
        *(f16x8*)(Pp + (((size_t)rbG * 128 + kbG) * 64 + lane) * 8) = fr;
      }
      WLGKM(0);  // reads done before next mb overwrites region
    }
  } else {
#pragma unroll
    for (int mb = 0; mb < 2; ++mb) {
      const int growb = m0 + mb * 32;
#pragma unroll
      for (int r = 0; r < 16; ++r) {
        const int row = (r & 3) + 8 * (r >> 2) + 4 * hi2;
        const int grow = growb + row;
        const size_t xb = (size_t)grow * NSITE + n0 + wn * 64 + l32;
        float s = acc[mb][0][r] * h2f(Xrow[xb]) + acc[mb][1][r] * h2f(Xrow[xb + 32]);
        s += __shfl_xor(s, 1);
        s += __shfl_xor(s, 2);
        s += __shfl_xor(s, 4);
        s += __shfl_xor(s, 8);
        s += __shfl_xor(s, 16);
        if (l32 == 0) atomicAdd(&out[grow], s);
      }
    }
  }
}

extern "C" void kernel_launch(void* const* d_in, const int* in_sizes, int n_in,
                              void* d_out, int out_size, void* d_ws, size_t ws_size,
                              hipStream_t stream) {
  const float* x = (const float*)d_in[0];
  const float* kern = (const float*)d_in[1];
  float* out = (float*)d_out;

  unsigned short* Wp   = (unsigned short*)d_ws;             // N*N fp16 packed
  unsigned short* Xp   = Wp + (size_t)NSITE * NSITE;        // NS*N packed
  unsigned short* Xrow = Xp + (size_t)NSAMP * NSITE;        // NS*N row-major
  unsigned short* P1   = Xrow + (size_t)NSAMP * NSITE;      // NS*N packed
  unsigned short* P2   = P1 + (size_t)NSAMP * NSITE;        // NS*N packed

  hipMemsetAsync(d_out, 0, (size_t)NSAMP * sizeof(float), stream);
  build_w_kernel<<<(NSITE * NSITE / 8) / 256, 256, 0, stream>>>(kern, Wp);
  build_x_kernel<<<(NSAMP * NSITE / 8) / 256, 256, 0, stream>>>(x, Xp, Xrow);

  // pass 1: z1 = x @ W^T ; P1 = pack(fp16(z1 * x))
  gemm_pass<0><<<2048, 256, 0, stream>>>(Xp, Wp, Xrow, P1, nullptr);
  // pass 2: z2 = P1 @ W^T ; P2 = pack(fp16(z2 * x))
  gemm_pass<0><<<2048, 256, 0, stream>>>(P1, Wp, Xrow, P2, nullptr);
  // pass 3: z3 = P2 @ W^T ; out[n] = sum_j z3 * x
  gemm_pass<1><<<2048, 256, 0, stream>>>(P2, Wp, Xrow, nullptr, out);
}

// Round 13
// 510.605 us; speedup vs baseline: 14.1092x; 1.0574x over previous
//
#include <hip/hip_runtime.h>
#include <stdint.h>

#define NSAMP 16384
#define NSITE 2048

typedef _Float16 f16x8 __attribute__((ext_vector_type(8)));
typedef float f32x16 __attribute__((ext_vector_type(16)));

__device__ __forceinline__ unsigned short f2h(float f) {
  _Float16 h = (_Float16)f;
  return __builtin_bit_cast(unsigned short, h);
}
__device__ __forceinline__ float h2f(unsigned short u) {
  return (float)__builtin_bit_cast(_Float16, u);
}

__device__ __forceinline__ void gload_lds16(const void* g, void* l) {
  __builtin_amdgcn_global_load_lds(
      (const __attribute__((address_space(1))) void*)g,
      (__attribute__((address_space(3))) void*)l, 16, 0, 0);
}

#define SBAR() __builtin_amdgcn_sched_barrier(0)
#define BAR()  do { SBAR(); __builtin_amdgcn_s_barrier(); SBAR(); } while (0)
#define WLGKM(N) do { asm volatile("s_waitcnt lgkmcnt(" #N ")" ::: "memory"); SBAR(); } while (0)
#define WVM(N)   do { asm volatile("s_waitcnt vmcnt(" #N ")" ::: "memory"); SBAR(); } while (0)

// ---------------------------------------------------------------------------
// Packed fragment-major layout for an [R x 2048] fp16 matrix M:
//   frag (rbG, kb) is 1 KiB: lane l holds M[rbG*32 + (l&31)][kb*16 + (l>>5)*8 + e]
//   short index = ((rbG*128 + kb)*64 + lane)*8 + e
// ---------------------------------------------------------------------------

__global__ void build_w_kernel(const float* __restrict__ kern,
                               unsigned short* __restrict__ Wp) {
  const int idx = blockIdx.x * blockDim.x + threadIdx.x;
  const int lane = idx & 63;
  const int kb = (idx >> 6) & 127;
  const int rbG = idx >> 13;
  const int j = rbG * 32 + (lane & 31);
  const int i0 = kb * 16 + (lane >> 5) * 8;
  const long long tri = (long long)j * (j - 1) / 2;
  unsigned short v[8];
#pragma unroll
  for (int e = 0; e < 8; ++e) {
    const int i = i0 + e;
    float f = (i < j) ? kern[tri + i] : 0.0f;
    v[e] = f2h(f);
  }
  ushort4* dst = (ushort4*)(Wp + (size_t)idx * 8);
  dst[0] = make_ushort4(v[0], v[1], v[2], v[3]);
  dst[1] = make_ushort4(v[4], v[5], v[6], v[7]);
}

__global__ void build_x_kernel(const float* __restrict__ x,
                               unsigned short* __restrict__ Xp,
                               unsigned short* __restrict__ Xrow) {
  const int idx = blockIdx.x * blockDim.x + threadIdx.x;
  const int row = idx >> 8;
  const int c8 = idx & 255;
  const float4 v0 = ((const float4*)x)[(size_t)idx * 2];
  const float4 v1 = ((const float4*)x)[(size_t)idx * 2 + 1];
  const ushort4 h0 = make_ushort4(f2h(v0.x), f2h(v0.y), f2h(v0.z), f2h(v0.w));
  const ushort4 h1 = make_ushort4(f2h(v1.x), f2h(v1.y), f2h(v1.z), f2h(v1.w));
  ushort4* dr = (ushort4*)(Xrow + (size_t)idx * 8);
  dr[0] = h0;
  dr[1] = h1;
  const int rbG = row >> 5, kb = c8 >> 1;
  const int lane = (c8 & 1) * 32 + (row & 31);
  ushort4* dp = (ushort4*)(Xp + (((size_t)rbG * 128 + kb) * 64 + lane) * 8);
  dp[0] = h0;
  dp[1] = h1;
}

// 256x256 tile, 8 waves (2M x 4N, wave 128x64), BK=64, 32x32x16 fp16 MFMA.
// m201-style 4-phase/K-tile schedule, ring of 8 x 16KB slots (128 KiB LDS):
// slot order per tile = {Ak0, Wk0, Ak1, Wk1}, double-buffered by tile parity.
// Phase: {ds-read frags | stage 1 slot} barrier; lgkmcnt(0); setprio+8 MFMA;
// counted WVM(4) only at pair boundaries (never 0 mid-loop); barrier.
template <int EPI>
__global__ __launch_bounds__(512, 2) void gemm_pass(
    const unsigned short* __restrict__ Ap, const unsigned short* __restrict__ Wp,
    const unsigned short* __restrict__ Xrow, unsigned short* __restrict__ Pp,
    float* __restrict__ out) {
  __shared__ unsigned short lds[65536];  // 128 KiB

  const int bid = blockIdx.x;  // 512 blocks
  // blocks 0..255: nt = 7,6,5,4 (heavy); 256..511: nt = 0,1,2,3 (light)
  const int cohort = (bid >> 6) & 3;
  const int nt = (bid >> 8) ? cohort : (7 - cohort);
  const int mt = bid & 63;
  const int m0 = mt * 256, n0 = nt * 256;

  const int tid = threadIdx.x, lane = tid & 63, wid = tid >> 6;
  const int wm = wid >> 2;   // 0..1: rows wm*128..
  const int wn = wid & 3;    // 0..3: cols wn*64..
  const int l32 = lane & 31, hi2 = lane >> 5;
  const int nkt = 4 * (nt + 1);  // K-tiles of 64 (strictly-lower-tri cut)

  f32x16 acc[4][2] = {};  // [mb][nb], 128 VGPR

  // per-thread staging sources: gload g covers frag f = g*8 + (tid>>6)
  const int f0 = tid >> 6;            // 0..7
  const int rb0 = f0 >> 1, kbo = f0 & 1;
  const int rbG0 = m0 >> 5, cbG0 = n0 >> 5;
  const unsigned short* pA0 = Ap + ((size_t)(rbG0 + rb0) * 128 + kbo) * 512 + (size_t)(tid & 63) * 8;
  const unsigned short* pA1 = Ap + ((size_t)(rbG0 + 4 + rb0) * 128 + kbo) * 512 + (size_t)(tid & 63) * 8;
  const unsigned short* pW0 = Wp + ((size_t)(cbG0 + rb0) * 128 + kbo) * 512 + (size_t)(tid & 63) * 8;
  const unsigned short* pW1 = Wp + ((size_t)(cbG0 + 4 + rb0) * 128 + kbo) * 512 + (size_t)(tid & 63) * 8;

  // stage slot p (0:Ak0 1:Wk0 2:Ak1 3:Wk1) for K-tile kt
  auto STAGE = [&](int p, int kt) {
    const size_t ko = (size_t)(4 * kt + ((p >> 1) << 1)) * 512;  // shorts
    const int base = ((kt & 1) << 16) | (p << 14);               // bytes
    const unsigned short* s0 = (p & 1) ? pW0 : pA0;
    const unsigned short* s1 = (p & 1) ? pW1 : pA1;
    gload_lds16(s0 + ko, (char*)lds + base + tid * 16);
    gload_lds16(s1 + ko, (char*)lds + base + 8192 + tid * 16);
  };

  // prologue: all 4 slots of tile 0; WVM(4) -> slots 0,1 landed
  STAGE(0, 0); STAGE(1, 0); STAGE(2, 0); STAGE(3, 0);
  WVM(4);
  BAR();

  for (int t = 0; t < nkt; ++t) {
    const int par = (t & 1) << 16;
    f16x8 fa[4][2], fw[2];
    const bool pre = (t + 1 < nkt);

#define READ_A(q)                                                                     \
  _Pragma("unroll") for (int mb = 0; mb < 4; ++mb) _Pragma("unroll") for (int kk = 0; \
                                                                          kk < 2;    \
                                                                          ++kk)      \
      fa[mb][kk] = *(const f16x8*)((char*)lds + par + ((q) << 15) +                   \
                                   (((wm * 4 + mb) * 2 + kk) << 10) + lane * 16);
#define READ_W(q, nb)                                               \
  _Pragma("unroll") for (int kk = 0; kk < 2; ++kk)                  \
      fw[kk] = *(const f16x8*)((char*)lds + par + ((q) << 15) +     \
                               16384 + (((wn * 2 + (nb)) * 2 + kk) << 10) + lane * 16);
#define MM(nb)                                                                            \
  do {                                                                                    \
    _Pragma("unroll") for (int mb = 0; mb < 4; ++mb) acc[mb][nb] =                        \
        __builtin_amdgcn_mfma_f32_32x32x16_f16(fa[mb][0], fw[0], acc[mb][nb], 0, 0, 0);   \
    _Pragma("unroll") for (int mb = 0; mb < 4; ++mb) acc[mb][nb] =                        \
        __builtin_amdgcn_mfma_f32_32x32x16_f16(fa[mb][1], fw[1], acc[mb][nb], 0, 0, 0);   \
  } while (0)

    // ---- phase 0: pair 0, nb 0
    READ_A(0); READ_W(0, 0);
    if (pre) STAGE(0, t + 1);
    BAR(); WLGKM(0);
    __builtin_amdgcn_s_setprio(1); MM(0); __builtin_amdgcn_s_setprio(0);
    BAR();
    // ---- phase 1: nb 1 (A frags held)
    READ_W(0, 1);
    if (pre) STAGE(1, t + 1);
    BAR(); WLGKM(0);
    __builtin_amdgcn_s_setprio(1); MM(1); __builtin_amdgcn_s_setprio(0);
    if (pre) { WVM(4); } else { WVM(0); }  // pair-1 slots landed
    BAR();
    // ---- phase 2: pair 1, nb 0
    READ_A(1); READ_W(1, 0);
    if (pre) STAGE(2, t + 1);
    BAR(); WLGKM(0);
    __builtin_amdgcn_s_setprio(1); MM(0); __builtin_amdgcn_s_setprio(0);
    BAR();
    // ---- phase 3: nb 1
    READ_W(1, 1);
    if (pre) STAGE(3, t + 1);
    BAR(); WLGKM(0);
    __builtin_amdgcn_s_setprio(1); MM(1); __builtin_amdgcn_s_setprio(0);
    if (pre) { WVM(4); }  // next tile's pair-0 slots landed
    BAR();
#undef READ_A
#undef READ_W
#undef MM
  }

  BAR();  // ring idle before epilogue reuses LDS

  // C/D layout 32x32: col = lane&31, row = (reg&3)+8*(reg>>2)+4*(lane>>5)
  const int ebase = wid * 4096;  // 8 waves x 4KB scratch
  if (EPI == 0) {
#pragma unroll
    for (int mb = 0; mb < 4; ++mb) {
      const int growb = m0 + wm * 128 + mb * 32;
#pragma unroll
      for (int nb = 0; nb < 2; ++nb)
#pragma unroll
        for (int r = 0; r < 16; ++r) {
          const int row = (r & 3) + 8 * (r >> 2) + 4 * hi2;
          const int col = nb * 32 + l32;
          const unsigned short xv =
              Xrow[(size_t)(growb + row) * NSITE + n0 + wn * 64 + col];
          const unsigned short pv = f2h(acc[mb][nb][r] * h2f(xv));
          const int cbyte = (col * 2) ^ ((row & 7) << 4);  // epi swizzle
          *(volatile unsigned short*)((char*)lds + ebase + row * 128 + cbyte) = pv;
        }
      WLGKM(0);  // wave-local visibility
      const int rbG = growb >> 5;
#pragma unroll
      for (int kbl = 0; kbl < 4; ++kbl) {
        const int cbyteR = (kbl * 32 + hi2 * 16) ^ ((l32 & 7) << 4);
        f16x8 fr = *(const f16x8*)((char*)lds + ebase + l32 * 128 + cbyteR);
        const int kbG = ((n0 + wn * 64) >> 4) + kbl;
        *(f16x8*)(Pp + (((size_t)rbG * 128 + kbG) * 64 + lane) * 8) = fr;
      }
      WLGKM(0);  // reads done before next mb overwrites region
    }
  } else {
#pragma unroll
    for (int mb = 0; mb < 4; ++mb) {
      const int growb = m0 + wm * 128 + mb * 32;
#pragma unroll
      for (int r = 0; r < 16; ++r) {
        const int row = (r & 3) + 8 * (r >> 2) + 4 * hi2;
        const int grow = growb + row;
        const size_t xb = (size_t)grow * NSITE + n0 + wn * 64 + l32;
        float s = acc[mb][0][r] * h2f(Xrow[xb]) + acc[mb][1][r] * h2f(Xrow[xb + 32]);
        s += __shfl_xor(s, 1);
        s += __shfl_xor(s, 2);
        s += __shfl_xor(s, 4);
        s += __shfl_xor(s, 8);
        s += __shfl_xor(s, 16);
        if (l32 == 0) atomicAdd(&out[grow], s);
      }
    }
  }
}

extern "C" void kernel_launch(void* const* d_in, const int* in_sizes, int n_in,
                              void* d_out, int out_size, void* d_ws, size_t ws_size,
                              hipStream_t stream) {
  const float* x = (const float*)d_in[0];
  const float* kern = (const float*)d_in[1];
  float* out = (float*)d_out;

  unsigned short* Wp   = (unsigned short*)d_ws;             // N*N fp16 packed
  unsigned short* Xp   = Wp + (size_t)NSITE * NSITE;        // NS*N packed
  unsigned short* Xrow = Xp + (size_t)NSAMP * NSITE;        // NS*N row-major
  unsigned short* P1   = Xrow + (size_t)NSAMP * NSITE;      // NS*N packed
  unsigned short* P2   = P1 + (size_t)NSAMP * NSITE;        // NS*N packed

  hipMemsetAsync(d_out, 0, (size_t)NSAMP * sizeof(float), stream);
  build_w_kernel<<<(NSITE * NSITE / 8) / 256, 256, 0, stream>>>(kern, Wp);
  build_x_kernel<<<(NSAMP * NSITE / 8) / 256, 256, 0, stream>>>(x, Xp, Xrow);

  // pass 1: z1 = x @ W^T ; P1 = pack(fp16(z1 * x))
  gemm_pass<0><<<512, 512, 0, stream>>>(Xp, Wp, Xrow, P1, nullptr);
  // pass 2: z2 = P1 @ W^T ; P2 = pack(fp16(z2 * x))
  gemm_pass<0><<<512, 512, 0, stream>>>(P1, Wp, Xrow, P2, nullptr);
  // pass 3: z3 = P2 @ W^T ; out[n] = sum_j z3 * x
  gemm_pass<1><<<512, 512, 0, stream>>>(P2, Wp, Xrow, nullptr, out);
}

// Round 14
// 419.856 us; speedup vs baseline: 17.1587x; 1.2161x over previous
//
#include <hip/hip_runtime.h>
#include <stdint.h>

#define NSAMP 16384
#define NSITE 2048
#define BM 128
#define BN 256
#define BK 64

typedef _Float16 f16x8 __attribute__((ext_vector_type(8)));
typedef float f32x16 __attribute__((ext_vector_type(16)));

__device__ __forceinline__ unsigned short f2h(float f) {
  _Float16 h = (_Float16)f;
  return __builtin_bit_cast(unsigned short, h);
}
__device__ __forceinline__ float h2f(unsigned short u) {
  return (float)__builtin_bit_cast(_Float16, u);
}

__device__ __forceinline__ void gload_lds16(const void* g, void* l) {
  __builtin_amdgcn_global_load_lds(
      (const __attribute__((address_space(1))) void*)g,
      (__attribute__((address_space(3))) void*)l, 16, 0, 0);
}

// ---------------------------------------------------------------------------
// Packed fragment-major layout for an [R x 2048] fp16 matrix M:
//   frag (rbG, kb) is 1 KiB: lane l holds M[rbG*32 + (l&31)][kb*16 + (l>>5)*8 + e]
//   short index = ((rbG*128 + kb)*64 + lane)*8 + e
// ---------------------------------------------------------------------------

__global__ void build_w_kernel(const float* __restrict__ kern,
                               unsigned short* __restrict__ Wp) {
  const int idx = blockIdx.x * blockDim.x + threadIdx.x;
  const int lane = idx & 63;
  const int kb = (idx >> 6) & 127;
  const int rbG = idx >> 13;
  const int j = rbG * 32 + (lane & 31);
  const int i0 = kb * 16 + (lane >> 5) * 8;
  const long long tri = (long long)j * (j - 1) / 2;
  unsigned short v[8];
#pragma unroll
  for (int e = 0; e < 8; ++e) {
    const int i = i0 + e;
    float f = (i < j) ? kern[tri + i] : 0.0f;
    v[e] = f2h(f);
  }
  ushort4* dst = (ushort4*)(Wp + (size_t)idx * 8);
  dst[0] = make_ushort4(v[0], v[1], v[2], v[3]);
  dst[1] = make_ushort4(v[4], v[5], v[6], v[7]);
}

__global__ void build_x_kernel(const float* __restrict__ x,
                               unsigned short* __restrict__ Xp,
                               unsigned short* __restrict__ Xrow) {
  const int idx = blockIdx.x * blockDim.x + threadIdx.x;
  const int row = idx >> 8;
  const int c8 = idx & 255;
  const float4 v0 = ((const float4*)x)[(size_t)idx * 2];
  const float4 v1 = ((const float4*)x)[(size_t)idx * 2 + 1];
  const ushort4 h0 = make_ushort4(f2h(v0.x), f2h(v0.y), f2h(v0.z), f2h(v0.w));
  const ushort4 h1 = make_ushort4(f2h(v1.x), f2h(v1.y), f2h(v1.z), f2h(v1.w));
  ushort4* dr = (ushort4*)(Xrow + (size_t)idx * 8);
  dr[0] = h0;
  dr[1] = h1;
  const int rbG = row >> 5, kb = c8 >> 1;
  const int lane = (c8 & 1) * 32 + (row & 31);
  ushort4* dp = (ushort4*)(Xp + (((size_t)rbG * 128 + kb) * 64 + lane) * 8);
  dp[0] = h0;
  dp[1] = h1;
}

// 128x256 tile, 8 waves (2M x 4N of 64x64), BK=64, 32x32x16 fp16 MFMA.
// PLAIN m97-style loop: stage 48KB -> __syncthreads -> compute -> __syncthreads.
// No inline asm, no sched_barrier, no setprio: compiler schedules waits.
// Packed frag-major layouts: staging linear-dest, all ds_reads uniform-base
// + lane*16 (zero bank conflicts). 2 blocks/CU (48KB LDS, <=128 VGPR).
template <int EPI>
__global__ __launch_bounds__(512, 4) void gemm_pass(
    const unsigned short* __restrict__ Ap, const unsigned short* __restrict__ Wp,
    const unsigned short* __restrict__ Xrow, unsigned short* __restrict__ Pp,
    float* __restrict__ out) {
  __shared__ unsigned short lds[24576];  // 48 KiB: A 16K | W 32K; epi reuses

  const int bid = blockIdx.x;  // 1024 blocks
  // balanced heavy/light nt pairing: g -> {7,0,6,1,5,2,4,3}
  const int g = bid >> 7;
  const int nt = (g & 1) ? (g >> 1) : (7 - (g >> 1));
  const int mt = bid & 127;
  const int m0 = mt * BM, n0 = nt * BN;

  const int tid = threadIdx.x, lane = tid & 63, wid = tid >> 6;
  const int wm = wid >> 2;   // 0..1: rows wm*64
  const int wn = wid & 3;    // 0..3: cols wn*64
  const int l32 = lane & 31, hi2 = lane >> 5;
  const int nkt = 4 * (nt + 1);  // K-tiles of 64, strictly-lower-tri cut

  f32x16 acc[2][2] = {};  // 64 VGPR

  // staging sources: round r covers frag f = r*8 + wid
  const int rbG0 = m0 >> 5, cbG0 = n0 >> 5;
  const unsigned short* srcA[2];
  int dstA[2];
#pragma unroll
  for (int r = 0; r < 2; ++r) {
    const int fA = r * 8 + wid;
    srcA[r] = Ap + ((size_t)(rbG0 + (fA >> 2)) * 128 + (fA & 3)) * 512 + lane * 8;
    dstA[r] = fA * 1024 + lane * 16;
  }
  const unsigned short* srcW[4];
  int dstW[4];
#pragma unroll
  for (int r = 0; r < 4; ++r) {
    const int fW = r * 8 + wid;
    srcW[r] = Wp + ((size_t)(cbG0 + (fW >> 2)) * 128 + (fW & 3)) * 512 + lane * 8;
    dstW[r] = 16384 + fW * 1024 + lane * 16;
  }

  for (int kt = 0; kt < nkt; ++kt) {
    const size_t ko = (size_t)kt * 2048;  // shorts: 4 kb of 512 per K-tile
#pragma unroll
    for (int r = 0; r < 2; ++r) gload_lds16(srcA[r] + ko, (char*)lds + dstA[r]);
#pragma unroll
    for (int r = 0; r < 4; ++r) gload_lds16(srcW[r] + ko, (char*)lds + dstW[r]);
    __syncthreads();
#pragma unroll
    for (int kbl = 0; kbl < 4; ++kbl) {
      f16x8 a0 = *(const f16x8*)((char*)lds + ((wm * 2 + 0) * 4 + kbl) * 1024 + lane * 16);
      f16x8 a1 = *(const f16x8*)((char*)lds + ((wm * 2 + 1) * 4 + kbl) * 1024 + lane * 16);
      f16x8 b0 = *(const f16x8*)((char*)lds + 16384 + ((wn * 2 + 0) * 4 + kbl) * 1024 + lane * 16);
      f16x8 b1 = *(const f16x8*)((char*)lds + 16384 + ((wn * 2 + 1) * 4 + kbl) * 1024 + lane * 16);
      acc[0][0] = __builtin_amdgcn_mfma_f32_32x32x16_f16(a0, b0, acc[0][0], 0, 0, 0);
      acc[0][1] = __builtin_amdgcn_mfma_f32_32x32x16_f16(a0, b1, acc[0][1], 0, 0, 0);
      acc[1][0] = __builtin_amdgcn_mfma_f32_32x32x16_f16(a1, b0, acc[1][0], 0, 0, 0);
      acc[1][1] = __builtin_amdgcn_mfma_f32_32x32x16_f16(a1, b1, acc[1][1], 0, 0, 0);
    }
    __syncthreads();
  }

  // C/D layout 32x32: col = lane&31, row = (reg&3)+8*(reg>>2)+4*(lane>>5)
  const int ebase = wid * 4096;  // 8 waves x 4KB scratch (reuses buffer)
  if (EPI == 0) {
#pragma unroll
    for (int mb = 0; mb < 2; ++mb) {
      const int growb = m0 + wm * 64 + mb * 32;
#pragma unroll
      for (int nb = 0; nb < 2; ++nb)
#pragma unroll
        for (int r = 0; r < 16; ++r) {
          const int row = (r & 3) + 8 * (r >> 2) + 4 * hi2;
          const int col = nb * 32 + l32;
          const unsigned short xv =
              Xrow[(size_t)(growb + row) * NSITE + n0 + wn * 64 + col];
          const unsigned short pv = f2h(acc[mb][nb][r] * h2f(xv));
          const int cbyte = (col * 2) ^ ((row & 7) << 4);  // epi swizzle
          *((unsigned short*)((char*)lds + ebase + row * 128 + cbyte)) = pv;
        }
      __syncthreads();
      const int rbG = growb >> 5;
#pragma unroll
      for (int kbl = 0; kbl < 4; ++kbl) {
        const int cbyteR = (kbl * 32 + hi2 * 16) ^ ((l32 & 7) << 4);
        f16x8 fr = *(const f16x8*)((char*)lds + ebase + l32 * 128 + cbyteR);
        const int kbG = ((n0 + wn * 64) >> 4) + kbl;
        *(f16x8*)(Pp + (((size_t)rbG * 128 + kbG) * 64 + lane) * 8) = fr;
      }
      __syncthreads();
    }
  } else {
#pragma unroll
    for (int mb = 0; mb < 2; ++mb) {
      const int growb = m0 + wm * 64 + mb * 32;
#pragma unroll
      for (int r = 0; r < 16; ++r) {
        const int row = (r & 3) + 8 * (r >> 2) + 4 * hi2;
        const int grow = growb + row;
        const size_t xb = (size_t)grow * NSITE + n0 + wn * 64 + l32;
        float s = acc[mb][0][r] * h2f(Xrow[xb]) + acc[mb][1][r] * h2f(Xrow[xb + 32]);
        s += __shfl_xor(s, 1);
        s += __shfl_xor(s, 2);
        s += __shfl_xor(s, 4);
        s += __shfl_xor(s, 8);
        s += __shfl_xor(s, 16);
        if (l32 == 0) atomicAdd(&out[grow], s);
      }
    }
  }
}

extern "C" void kernel_launch(void* const* d_in, const int* in_sizes, int n_in,
                              void* d_out, int out_size, void* d_ws, size_t ws_size,
                              hipStream_t stream) {
  const float* x = (const float*)d_in[0];
  const float* kern = (const float*)d_in[1];
  float* out = (float*)d_out;

  unsigned short* Wp   = (unsigned short*)d_ws;             // N*N fp16 packed
  unsigned short* Xp   = Wp + (size_t)NSITE * NSITE;        // NS*N packed
  unsigned short* Xrow = Xp + (size_t)NSAMP * NSITE;        // NS*N row-major
  unsigned short* P1   = Xrow + (size_t)NSAMP * NSITE;      // NS*N packed
  unsigned short* P2   = P1 + (size_t)NSAMP * NSITE;        // NS*N packed

  hipMemsetAsync(d_out, 0, (size_t)NSAMP * sizeof(float), stream);
  build_w_kernel<<<(NSITE * NSITE / 8) / 256, 256, 0, stream>>>(kern, Wp);
  build_x_kernel<<<(NSAMP * NSITE / 8) / 256, 256, 0, stream>>>(x, Xp, Xrow);

  // pass 1: z1 = x @ W^T ; P1 = pack(fp16(z1 * x))
  gemm_pass<0><<<1024, 512, 0, stream>>>(Xp, Wp, Xrow, P1, nullptr);
  // pass 2: z2 = P1 @ W^T ; P2 = pack(fp16(z2 * x))
  gemm_pass<0><<<1024, 512, 0, stream>>>(P1, Wp, Xrow, P2, nullptr);
  // pass 3: z3 = P2 @ W^T ; out[n] = sum_j z3 * x
  gemm_pass<1><<<1024, 512, 0, stream>>>(P2, Wp, Xrow, nullptr, out);
}

// Round 15
// 409.474 us; speedup vs baseline: 17.5938x; 1.0254x over previous
//
#include <hip/hip_runtime.h>
#include <stdint.h>

#define NSAMP 16384
#define NSITE 2048
#define BM 128
#define BN 256
#define BK 32

typedef _Float16 f16x8 __attribute__((ext_vector_type(8)));
typedef float f32x16 __attribute__((ext_vector_type(16)));

__device__ __forceinline__ unsigned short f2h(float f) {
  _Float16 h = (_Float16)f;
  return __builtin_bit_cast(unsigned short, h);
}
__device__ __forceinline__ float h2f(unsigned short u) {
  return (float)__builtin_bit_cast(_Float16, u);
}

__device__ __forceinline__ void gload_lds16(const void* g, void* l) {
  __builtin_amdgcn_global_load_lds(
      (const __attribute__((address_space(1))) void*)g,
      (__attribute__((address_space(3))) void*)l, 16, 0, 0);
}

// ---------------------------------------------------------------------------
// Packed fragment-major layout for an [R x 2048] fp16 matrix M:
//   frag (rbG, kb) is 1 KiB: lane l holds M[rbG*32 + (l&31)][kb*16 + (l>>5)*8 + e]
//   short index = ((rbG*128 + kb)*64 + lane)*8 + e
// ---------------------------------------------------------------------------

__global__ void build_w_kernel(const float* __restrict__ kern,
                               unsigned short* __restrict__ Wp) {
  const int idx = blockIdx.x * blockDim.x + threadIdx.x;
  const int lane = idx & 63;
  const int kb = (idx >> 6) & 127;
  const int rbG = idx >> 13;
  const int j = rbG * 32 + (lane & 31);
  const int i0 = kb * 16 + (lane >> 5) * 8;
  const long long tri = (long long)j * (j - 1) / 2;
  unsigned short v[8];
#pragma unroll
  for (int e = 0; e < 8; ++e) {
    const int i = i0 + e;
    float f = (i < j) ? kern[tri + i] : 0.0f;
    v[e] = f2h(f);
  }
  ushort4* dst = (ushort4*)(Wp + (size_t)idx * 8);
  dst[0] = make_ushort4(v[0], v[1], v[2], v[3]);
  dst[1] = make_ushort4(v[4], v[5], v[6], v[7]);
}

__global__ void build_x_kernel(const float* __restrict__ x,
                               unsigned short* __restrict__ Xp,
                               unsigned short* __restrict__ Xrow) {
  const int idx = blockIdx.x * blockDim.x + threadIdx.x;
  const int row = idx >> 8;
  const int c8 = idx & 255;
  const float4 v0 = ((const float4*)x)[(size_t)idx * 2];
  const float4 v1 = ((const float4*)x)[(size_t)idx * 2 + 1];
  const ushort4 h0 = make_ushort4(f2h(v0.x), f2h(v0.y), f2h(v0.z), f2h(v0.w));
  const ushort4 h1 = make_ushort4(f2h(v1.x), f2h(v1.y), f2h(v1.z), f2h(v1.w));
  ushort4* dr = (ushort4*)(Xrow + (size_t)idx * 8);
  dr[0] = h0;
  dr[1] = h1;
  const int rbG = row >> 5, kb = c8 >> 1;
  const int lane = (c8 & 1) * 32 + (row & 31);
  ushort4* dp = (ushort4*)(Xp + (((size_t)rbG * 128 + kb) * 64 + lane) * 8);
  dp[0] = h0;
  dp[1] = h1;
}

// 128x256 tile, 8 waves (2M x 4N of 64x64), BK=32, 32x32x16 fp16 MFMA.
// Double-buffered plain loop: STAGE(t+1, buf^1) issued BEFORE compute(t), so
// the compiler's vmcnt drain at the end barrier lands after ~2000 cyc of
// compute (DMA latency hidden). No inline asm / sched_barrier / setprio.
// Packed frag-major layouts: linear DMA dest, all ds_reads uniform-base
// + lane*16 (zero bank conflicts). 48 KiB LDS -> 3 blocks/CU.
template <int EPI>
__global__ __launch_bounds__(512, 4) void gemm_pass(
    const unsigned short* __restrict__ Ap, const unsigned short* __restrict__ Wp,
    const unsigned short* __restrict__ Xrow, unsigned short* __restrict__ Pp,
    float* __restrict__ out) {
  __shared__ unsigned short lds[24576];  // 2 x 24 KiB (A 8K | W 16K per buf)

  const int bid = blockIdx.x;  // 1024 blocks
  // balanced heavy/light nt pairing: g -> {7,0,6,1,5,2,4,3}
  const int g = bid >> 7;
  const int nt = (g & 1) ? (g >> 1) : (7 - (g >> 1));
  const int mt = bid & 127;
  const int m0 = mt * BM, n0 = nt * BN;

  const int tid = threadIdx.x, lane = tid & 63, wid = tid >> 6;
  const int wm = wid >> 2;   // 0..1: rows wm*64
  const int wn = wid & 3;    // 0..3: cols wn*64
  const int l32 = lane & 31, hi2 = lane >> 5;
  const int nkt = 8 * (nt + 1);  // K-steps of 32, strictly-lower-tri cut

  f32x16 acc[2][2] = {};  // 64 VGPR

  // staging sources (1 A-gload + 2 W-gloads per thread per K-step)
  const int rbG0 = m0 >> 5, cbG0 = n0 >> 5;
  const int fA = tid >> 6;  // 0..7: rb = fA>>1, kb = fA&1
  const unsigned short* srcA =
      Ap + ((size_t)(rbG0 + (fA >> 1)) * 128 + (fA & 1)) * 512 + lane * 8;
  const unsigned short* srcW[2];
#pragma unroll
  for (int r = 0; r < 2; ++r) {
    const int fW = r * 8 + (tid >> 6);  // 0..15: cb = fW>>1, kb = fW&1
    srcW[r] = Wp + ((size_t)(cbG0 + (fW >> 1)) * 128 + (fW & 1)) * 512 + lane * 8;
  }

  auto STAGE = [&](int kt, int bufbase) {
    const size_t ko = (size_t)kt * 1024;  // shorts: 2 kb of 512 per K-step
    gload_lds16(srcA + ko, (char*)lds + bufbase + tid * 16);
    gload_lds16(srcW[0] + ko, (char*)lds + bufbase + 8192 + tid * 16);
    gload_lds16(srcW[1] + ko, (char*)lds + bufbase + 16384 + tid * 16);
  };

  STAGE(0, 0);
  __syncthreads();  // prologue drain (exposed once)

  for (int kt = 0; kt < nkt; ++kt) {
    const int cur = (kt & 1) * 24576;
    if (kt + 1 < nkt) STAGE(kt + 1, cur ^ 24576);
#pragma unroll
    for (int kbl = 0; kbl < 2; ++kbl) {
      f16x8 a0 = *(const f16x8*)((char*)lds + cur + (((wm * 2 + 0) * 2 + kbl)) * 1024 + lane * 16);
      f16x8 a1 = *(const f16x8*)((char*)lds + cur + (((wm * 2 + 1) * 2 + kbl)) * 1024 + lane * 16);
      f16x8 b0 = *(const f16x8*)((char*)lds + cur + 8192 + (((wn * 2 + 0) * 2 + kbl)) * 1024 + lane * 16);
      f16x8 b1 = *(const f16x8*)((char*)lds + cur + 8192 + (((wn * 2 + 1) * 2 + kbl)) * 1024 + lane * 16);
      acc[0][0] = __builtin_amdgcn_mfma_f32_32x32x16_f16(a0, b0, acc[0][0], 0, 0, 0);
      acc[0][1] = __builtin_amdgcn_mfma_f32_32x32x16_f16(a0, b1, acc[0][1], 0, 0, 0);
      acc[1][0] = __builtin_amdgcn_mfma_f32_32x32x16_f16(a1, b0, acc[1][0], 0, 0, 0);
      acc[1][1] = __builtin_amdgcn_mfma_f32_32x32x16_f16(a1, b1, acc[1][1], 0, 0, 0);
    }
    __syncthreads();  // drain lands after compute: DMA latency hidden
  }

  // C/D layout 32x32: col = lane&31, row = (reg&3)+8*(reg>>2)+4*(lane>>5)
  const int ebase = wid * 4096;  // 8 waves x 4KB scratch (reuses buffers)
  if (EPI == 0) {
#pragma unroll
    for (int mb = 0; mb < 2; ++mb) {
      const int growb = m0 + wm * 64 + mb * 32;
#pragma unroll
      for (int nb = 0; nb < 2; ++nb)
#pragma unroll
        for (int r = 0; r < 16; ++r) {
          const int row = (r & 3) + 8 * (r >> 2) + 4 * hi2;
          const int col = nb * 32 + l32;
          const unsigned short xv =
              Xrow[(size_t)(growb + row) * NSITE + n0 + wn * 64 + col];
          const unsigned short pv = f2h(acc[mb][nb][r] * h2f(xv));
          const int cbyte = (col * 2) ^ ((row & 7) << 4);  // epi swizzle
          *((unsigned short*)((char*)lds + ebase + row * 128 + cbyte)) = pv;
        }
      __syncthreads();
      const int rbG = growb >> 5;
#pragma unroll
      for (int kbl = 0; kbl < 4; ++kbl) {
        const int cbyteR = (kbl * 32 + hi2 * 16) ^ ((l32 & 7) << 4);
        f16x8 fr = *(const f16x8*)((char*)lds + ebase + l32 * 128 + cbyteR);
        const int kbG = ((n0 + wn * 64) >> 4) + kbl;
        *(f16x8*)(Pp + (((size_t)rbG * 128 + kbG) * 64 + lane) * 8) = fr;
      }
      __syncthreads();
    }
  } else {
#pragma unroll
    for (int mb = 0; mb < 2; ++mb) {
      const int growb = m0 + wm * 64 + mb * 32;
#pragma unroll
      for (int r = 0; r < 16; ++r) {
        const int row = (r & 3) + 8 * (r >> 2) + 4 * hi2;
        const int grow = growb + row;
        const size_t xb = (size_t)grow * NSITE + n0 + wn * 64 + l32;
        float s = acc[mb][0][r] * h2f(Xrow[xb]) + acc[mb][1][r] * h2f(Xrow[xb + 32]);
        s += __shfl_xor(s, 1);
        s += __shfl_xor(s, 2);
        s += __shfl_xor(s, 4);
        s += __shfl_xor(s, 8);
        s += __shfl_xor(s, 16);
        if (l32 == 0) atomicAdd(&out[grow], s);
      }
    }
  }
}

extern "C" void kernel_launch(void* const* d_in, const int* in_sizes, int n_in,
                              void* d_out, int out_size, void* d_ws, size_t ws_size,
                              hipStream_t stream) {
  const float* x = (const float*)d_in[0];
  const float* kern = (const float*)d_in[1];
  float* out = (float*)d_out;

  unsigned short* Wp   = (unsigned short*)d_ws;             // N*N fp16 packed
  unsigned short* Xp   = Wp + (size_t)NSITE * NSITE;        // NS*N packed
  unsigned short* Xrow = Xp + (size_t)NSAMP * NSITE;        // NS*N row-major
  unsigned short* P1   = Xrow + (size_t)NSAMP * NSITE;      // NS*N packed
  unsigned short* P2   = P1 + (size_t)NSAMP * NSITE;        // NS*N packed

  hipMemsetAsync(d_out, 0, (size_t)NSAMP * sizeof(float), stream);
  build_w_kernel<<<(NSITE * NSITE / 8) / 256, 256, 0, stream>>>(kern, Wp);
  build_x_kernel<<<(NSAMP * NSITE / 8) / 256, 256, 0, stream>>>(x, Xp, Xrow);

  // pass 1: z1 = x @ W^T ; P1 = pack(fp16(z1 * x))
  gemm_pass<0><<<1024, 512, 0, stream>>>(Xp, Wp, Xrow, P1, nullptr);
  // pass 2: z2 = P1 @ W^T ; P2 = pack(fp16(z2 * x))
  gemm_pass<0><<<1024, 512, 0, stream>>>(P1, Wp, Xrow, P2, nullptr);
  // pass 3: z3 = P2 @ W^T ; out[n] = sum_j z3 * x
  gemm_pass<1><<<1024, 512, 0, stream>>>(P2, Wp, Xrow, nullptr, out);
}